// Round 10
// baseline (95.461 us; speedup 1.0000x reference)
//
#include <hip/hip_runtime.h>

// 3D trilinear warp (grid_sample, align_corners=True, border padding).
// image: (B=2, 1, 160, 192, 192) f32 | ddf: (B,3,D,H,W) f32 (dz,dy,dx voxels)
//
// Round-10: 2-block-per-CU co-residency.
//  - 512-thread block, tile 32(x) x 8(y) x 8(z), 4 voxels/thread.
//  - One-shot LDS window: 16 slices of 52x22 f32 = 73.2 KB (slot = z & 15,
//    bijective over [zlo-4, zlo+12)). Block total ~78.4 KB -> TWO blocks
//    resident per CU: one block's staging/barriers overlap the other's
//    compute (the R9 stall was 1-block/CU phase serialization).
//  - Safe corner range z0 in [zlo-4, zlo+10]; ~5% of voxels miss the
//    window -> push {s, dx, dy, dz} (float4) into an LDS queue; epilogue
//    gathers them from global (L2-hot), never re-reading ddf from HBM.
//  - Branchless LDS reads in the main loop (clamped offsets); NT loads for
//    ddf, NT store for output; XCD-chunked bijective swizzle (5760 %8==0).

typedef float f32x4 __attribute__((ext_vector_type(4)));
typedef float f32x2 __attribute__((ext_vector_type(2)));

constexpr int D_ = 160, H_ = 192, W_ = 192;
constexpr int HW_ = H_ * W_;
constexpr int N_  = D_ * HW_;

constexpr int TX_ = 32, TY_ = 8, ZR_ = 8;
constexpr int XT_ = W_ / TX_;               // 6
constexpr int YT_ = H_ / TY_;               // 24
constexpr int ZT_ = D_ / ZR_;               // 20
constexpr int NBLK_ = XT_ * YT_ * ZT_ * 2;  // 5760 (%8==0)

constexpr int RX_ = 52, RY_ = 22, NZ_ = 16;
constexpr int SLICE_ = RX_ * RY_;           // 1144 floats (4576 B, 16-aligned)
constexpr int CPS_ = SLICE_ / 4;            // 286 dwordx4 chunks per slice
constexpr int CPR_ = RX_ / 4;               // 13 chunks per row
constexpr int QCAP_ = 320;                  // mean ~113 misses/block

__global__ __launch_bounds__(512) void warp3d_kernel(
    const float* __restrict__ img,
    const float* __restrict__ ddf,
    float* __restrict__ out)
{
    __shared__ float tile[NZ_ * SLICE_];    // 73,216 B
    __shared__ f32x4 qdat[QCAP_];           // 5,120 B
    __shared__ int   qcount;

    constexpr int CPX = NBLK_ / 8;          // 720
    int bid = blockIdx.x;
    int swz = (bid & 7) * CPX + (bid >> 3);

    int tx = swz % XT_;  int t1 = swz / XT_;
    int ty = t1 % YT_;   int t2 = t1 / YT_;
    int zh = t2 % ZT_;   int b  = t2 / ZT_;

    int zlo = zh * ZR_;
    int rx = min(max(tx * TX_ - 8, 0), W_ - RX_);   // always %4==0
    int ry = min(max(ty * TY_ - 7, 0), H_ - RY_);

    const float* im = img + (size_t)b * N_;
    const float* dp = ddf + (size_t)b * 3 * N_;
    float*       op = out + (size_t)b * N_;

    int tid = threadIdx.x;
    int xi = tid & 31;
    int yy = (tid >> 5) & 7;
    int zz = tid >> 8;                      // 0..1

    int x = tx * TX_ + xi;
    int y = ty * TY_ + yy;
    int zbase = zlo + zz * 4;               // thread covers z = zbase..zbase+3
    int s0 = (zbase * H_ + y) * W_ + x;

    // ---- ddf loads for 4 voxels (latency hides under staging) ----
    float ddz[4], ddy[4], ddx[4];
#pragma unroll
    for (int k = 0; k < 4; ++k) {
        int s = s0 + k * HW_;
        ddz[k] = __builtin_nontemporal_load(dp + s);
        ddy[k] = __builtin_nontemporal_load(dp + N_ + s);
        ddx[k] = __builtin_nontemporal_load(dp + 2 * N_ + s);
    }

    // ---- one-shot staging of slices [max(0,zlo-4), min(D,zlo+12)) ----
    if (tid == 0) qcount = 0;
    int pz0 = max(0, zlo - 4);
    int pz1 = min(D_, zlo + 12);
    int pcnt = (pz1 - pz0) * CPS_;
    for (int c = tid; c < pcnt; c += 512) {
        int si  = c / CPS_;
        int rem = c - si * CPS_;
        int zs  = pz0 + si;
        int row = rem / CPR_;
        int col = rem - row * CPR_;
        f32x4 v = *(const f32x4*)(im + (zs * H_ + ry + row) * W_ + rx + col * 4);
        *(f32x4*)&tile[(zs & (NZ_ - 1)) * SLICE_ + rem * 4] = v;
    }
    __syncthreads();

    // global gather (overflow + epilogue path)
    auto gglobal = [&](int vx, int vy, int vz,
                       float gdx, float gdy, float gdz) -> float {
        float ix = fminf(fmaxf((float)vx + gdx, 0.f), (float)(W_ - 1));
        float iy = fminf(fmaxf((float)vy + gdy, 0.f), (float)(H_ - 1));
        float iz = fminf(fmaxf((float)vz + gdz, 0.f), (float)(D_ - 1));
        int x0 = min((int)ix, W_ - 2);
        int y0 = min((int)iy, H_ - 2);
        int z0 = min((int)iz, D_ - 2);
        float wx = ix - (float)x0;
        float wy = iy - (float)y0;
        float wz = iz - (float)z0;
        const float* p = im + (z0 * HW_ + y0 * W_ + x0);
        f32x2 a = *(const f32x2*)(p);
        f32x2 c = *(const f32x2*)(p + W_);
        f32x2 e = *(const f32x2*)(p + HW_);
        f32x2 f = *(const f32x2*)(p + HW_ + W_);
        float c00 = a.x + (a.y - a.x) * wx;
        float c01 = c.x + (c.y - c.x) * wx;
        float c10 = e.x + (e.y - e.x) * wx;
        float c11 = f.x + (f.y - f.x) * wx;
        float c0 = c00 + (c01 - c00) * wy;
        float c1 = c10 + (c11 - c10) * wy;
        return c0 + (c1 - c0) * wz;
    };

    // ---- straight-line compute: 4 voxels/thread ----
#pragma unroll
    for (int k = 0; k < 4; ++k) {
        int z = zbase + k;
        int s = s0 + k * HW_;

        float ix = fminf(fmaxf((float)x + ddx[k], 0.f), (float)(W_ - 1));
        float iy = fminf(fmaxf((float)y + ddy[k], 0.f), (float)(H_ - 1));
        float iz = fminf(fmaxf((float)z + ddz[k], 0.f), (float)(D_ - 1));

        int x0 = min((int)ix, W_ - 2);
        int y0 = min((int)iy, H_ - 2);
        int z0 = min((int)iz, D_ - 2);
        float wx = ix - (float)x0;
        float wy = iy - (float)y0;
        float wz = iz - (float)z0;

        int ux = x0 - rx, uy = y0 - ry, uz = z0 - (zlo - 4);
        bool in = ((unsigned)ux <= (unsigned)(RX_ - 2)) &
                  ((unsigned)uy <= (unsigned)(RY_ - 2)) &
                  ((unsigned)uz <= 14u);

        // branchless LDS read (clamped; garbage when !in, discarded)
        int uxc = min(max(ux, 0), RX_ - 2);
        int uyc = min(max(uy, 0), RY_ - 2);
        int uzc = min(max(uz, 0), 14);
        int z0c = (zlo - 4) + uzc;
        int base = uyc * RX_ + uxc;
        int o0 = (z0c & (NZ_ - 1)) * SLICE_ + base;
        int o1 = ((z0c + 1) & (NZ_ - 1)) * SLICE_ + base;

        float v000 = tile[o0];       float v001 = tile[o0 + 1];
        float v010 = tile[o0 + RX_]; float v011 = tile[o0 + RX_ + 1];
        float v100 = tile[o1];       float v101 = tile[o1 + 1];
        float v110 = tile[o1 + RX_]; float v111 = tile[o1 + RX_ + 1];

        float c00 = v000 + (v001 - v000) * wx;
        float c01 = v010 + (v011 - v010) * wx;
        float c10 = v100 + (v101 - v100) * wx;
        float c11 = v110 + (v111 - v110) * wx;
        float c0 = c00 + (c01 - c00) * wy;
        float c1 = c10 + (c11 - c10) * wy;
        float res = c0 + (c1 - c0) * wz;

        bool do_store = in;
        if (!in) {
            int idx = atomicAdd(&qcount, 1);
            if (idx < QCAP_) {
                qdat[idx] = f32x4{__int_as_float(s), ddx[k], ddy[k], ddz[k]};
            } else {
                res = gglobal(x, y, z, ddx[k], ddy[k], ddz[k]);
                do_store = true;
            }
        }
        if (do_store) __builtin_nontemporal_store(res, op + s);
    }

    __syncthreads();

    // ---- epilogue: resolve queued misses (ddf from queue, gathers L2-hot) --
    int n = min(qcount, QCAP_);
    for (int i = tid; i < n; i += 512) {
        f32x4 q = qdat[i];
        int sq = __float_as_int(q.x);
        int zq = sq / HW_;
        int rq = sq - zq * HW_;
        int yq = rq / W_;
        int xq = rq - yq * W_;
        float res = gglobal(xq, yq, zq, q.y, q.z, q.w);
        op[sq] = res;
    }
}

extern "C" void kernel_launch(void* const* d_in, const int* in_sizes, int n_in,
                              void* d_out, int out_size, void* d_ws, size_t ws_size,
                              hipStream_t stream) {
    const float* img = (const float*)d_in[0];
    const float* ddf = (const float*)d_in[1];
    float*       out = (float*)d_out;

    warp3d_kernel<<<NBLK_, 512, 0, stream>>>(img, ddf, out);
}

// Round 11
// 85.301 us; speedup vs baseline: 1.1191x; 1.1191x over previous
//
#include <hip/hip_runtime.h>

// 3D trilinear warp (grid_sample, align_corners=True, border padding).
// image: (B=2, 1, 160, 192, 192) f32 | ddf: (B,3,D,H,W) f32 (dz,dy,dx voxels)
//
// Round-11: R9 geometry (best) + split-phase staging pipeline + VALU trim.
//  - Grid 6(x) x 24(y) x 8(zh) x 2(b) = 2304 blocks = exactly 9/CU, 1024 thr.
//  - Window: 32 slices [zlo-4, zlo+28) of a 52x23 region, slot = z-(zlo-4)
//    (direct mapping, no & wrap). 153 KB LDS.
//  - Phase A: stage slices [zlo-4, zlo+12) -> barrier -> ISSUE upper-16-slice
//    loads into regs (T14) -> compute k=0,1 (z<=zlo+7, window-top uz<=14)
//    -> commit regs to LDS slots 16..31 (disjoint from phase-A reads) ->
//    barrier -> compute k=2..4 with full window (uz<=30).
//  - Branchless LDS reads via single final-offset clamp (garbage aliased
//    reads only on miss, discarded). Misses push {s,dx,dy,dz} to LDS queue;
//    epilogue gathers from global (L2-hot), never re-reads ddf from HBM.
//  - XCD-chunked bijective swizzle kept (2304 % 8 == 0).

typedef float f32x4 __attribute__((ext_vector_type(4)));
typedef float f32x2 __attribute__((ext_vector_type(2)));

constexpr int D_ = 160, H_ = 192, W_ = 192;
constexpr int HW_ = H_ * W_;
constexpr int N_  = D_ * HW_;

constexpr int TX_ = 32, TY_ = 8;
constexpr int XT_ = W_ / TX_;               // 6
constexpr int YT_ = H_ / TY_;               // 24
constexpr int ZH_ = 8;
constexpr int ZRUN_ = D_ / ZH_;             // 20
constexpr int NBLK_ = XT_ * YT_ * ZH_ * 2;  // 2304 = 9 * 256 exactly

constexpr int RX_ = 52, RY_ = 23, NZ_ = 32;
constexpr int SLICE_ = RX_ * RY_;           // 1196 floats
constexpr int CPS_ = SLICE_ / 4;            // 299 dwordx4 chunks per slice
constexpr int CPR_ = RX_ / 4;               // 13 chunks per row
constexpr int LIM_ = NZ_ * SLICE_ - RX_ - 2;// 38218: max safe base offset
constexpr int QCAP_ = 512;

__global__ __launch_bounds__(1024) void warp3d_kernel(
    const float* __restrict__ img,
    const float* __restrict__ ddf,
    float* __restrict__ out)
{
    __shared__ float tile[NZ_ * SLICE_];    // 153,088 B
    __shared__ f32x4 qdat[QCAP_];           // 8,192 B
    __shared__ int   qcount;

    constexpr int CPX = NBLK_ / 8;          // 288
    int bid = blockIdx.x;
    int swz = (bid & 7) * CPX + (bid >> 3);

    int tx = swz % XT_;  int t1 = swz / XT_;
    int ty = t1 % YT_;   int t2 = t1 / YT_;
    int zh = t2 % ZH_;   int b  = t2 / ZH_;

    int zlo = zh * ZRUN_;
    int vz0 = zlo - 4;                      // virtual window origin (may be <0)
    int rx = min(max(tx * TX_ - 8, 0), W_ - RX_);
    int ry = min(max(ty * TY_ - 7, 0), H_ - RY_);

    const float* im = img + (size_t)b * N_;
    const float* dp = ddf + (size_t)b * 3 * N_;
    float*       op = out + (size_t)b * N_;

    int tid = threadIdx.x;
    int xi = tid & 31;
    int yy = (tid >> 5) & 7;
    int zz = tid >> 8;                      // 0..3

    int x = tx * TX_ + xi;
    int y = ty * TY_ + yy;
    int s0 = ((zlo + zz) * H_ + y) * W_ + x;

    // ---- ddf loads for all 5 voxels (latency hides under phase-A staging) --
    float ddz[5], ddy[5], ddxv[5];
#pragma unroll
    for (int k = 0; k < 5; ++k) {
        int s = s0 + k * 4 * HW_;
        ddz[k]  = __builtin_nontemporal_load(dp + s);
        ddy[k]  = __builtin_nontemporal_load(dp + N_ + s);
        ddxv[k] = __builtin_nontemporal_load(dp + 2 * N_ + s);
    }

    if (tid == 0) qcount = 0;

    // ---- phase A: stage slices [max(0,vz0), zlo+12) -> slots [.,16) ----
    int pzA0 = max(0, vz0);
    int pcntA = (zlo + 12 - pzA0) * CPS_;
    for (int c = tid; c < pcntA; c += 1024) {
        int si  = c / CPS_;
        int rem = c - si * CPS_;
        int zs  = pzA0 + si;
        int row = rem / CPR_;
        int col = rem - row * CPR_;
        f32x4 v = *(const f32x4*)(im + (zs * H_ + ry + row) * W_ + rx + col * 4);
        *(f32x4*)&tile[(zs - vz0) * SLICE_ + rem * 4] = v;
    }
    __syncthreads();

    // global gather (overflow + epilogue path)
    auto gglobal = [&](int vx, int vy, int vz,
                       float gdx, float gdy, float gdz) -> float {
        float ix = fminf(fmaxf((float)vx + gdx, 0.f), (float)(W_ - 1));
        float iy = fminf(fmaxf((float)vy + gdy, 0.f), (float)(H_ - 1));
        float iz = fminf(fmaxf((float)vz + gdz, 0.f), (float)(D_ - 1));
        int x0 = min((int)ix, W_ - 2);
        int y0 = min((int)iy, H_ - 2);
        int z0 = min((int)iz, D_ - 2);
        float wx = ix - (float)x0;
        float wy = iy - (float)y0;
        float wz = iz - (float)z0;
        const float* p = im + (z0 * HW_ + y0 * W_ + x0);
        f32x2 a = *(const f32x2*)(p);
        f32x2 c = *(const f32x2*)(p + W_);
        f32x2 e = *(const f32x2*)(p + HW_);
        f32x2 f = *(const f32x2*)(p + HW_ + W_);
        float c00 = a.x + (a.y - a.x) * wx;
        float c01 = c.x + (c.y - c.x) * wx;
        float c10 = e.x + (e.y - e.x) * wx;
        float c11 = f.x + (f.y - f.x) * wx;
        float c0 = c00 + (c01 - c00) * wy;
        float c1 = c10 + (c11 - c10) * wy;
        return c0 + (c1 - c0) * wz;
    };

    // one voxel: LDS window read (single final-offset clamp) + queue on miss
    auto process = [&](int z, int s, float gdx, float gdy, float gdz,
                       int uzTop) {
        float ix = fminf(fmaxf((float)x + gdx, 0.f), (float)(W_ - 1));
        float iy = fminf(fmaxf((float)y + gdy, 0.f), (float)(H_ - 1));
        float iz = fminf(fmaxf((float)z + gdz, 0.f), (float)(D_ - 1));

        int x0 = min((int)ix, W_ - 2);
        int y0 = min((int)iy, H_ - 2);
        int z0 = min((int)iz, D_ - 2);
        float wx = ix - (float)x0;
        float wy = iy - (float)y0;
        float wz = iz - (float)z0;

        int ux = x0 - rx, uy = y0 - ry, uz = z0 - vz0;
        bool in = ((unsigned)ux <= (unsigned)(RX_ - 2)) &
                  ((unsigned)uy <= (unsigned)(RY_ - 2)) &
                  ((unsigned)uz <= (unsigned)uzTop);

        int o0 = uz * SLICE_ + uy * RX_ + ux;   // raw; may be out of range
        o0 = min(max(o0, 0), LIM_);             // memory-safe (garbage on miss)
        int o1 = min(o0 + SLICE_, LIM_);

        float v000 = tile[o0];       float v001 = tile[o0 + 1];
        float v010 = tile[o0 + RX_]; float v011 = tile[o0 + RX_ + 1];
        float v100 = tile[o1];       float v101 = tile[o1 + 1];
        float v110 = tile[o1 + RX_]; float v111 = tile[o1 + RX_ + 1];

        float c00 = v000 + (v001 - v000) * wx;
        float c01 = v010 + (v011 - v010) * wx;
        float c10 = v100 + (v101 - v100) * wx;
        float c11 = v110 + (v111 - v110) * wx;
        float c0 = c00 + (c01 - c00) * wy;
        float c1 = c10 + (c11 - c10) * wy;
        float res = c0 + (c1 - c0) * wz;

        bool do_store = in;
        if (!in) {
            int idx = atomicAdd(&qcount, 1);
            if (idx < QCAP_) {
                qdat[idx] = f32x4{__int_as_float(s), gdx, gdy, gdz};
            } else {
                res = gglobal(x, y, z, gdx, gdy, gdz);
                do_store = true;
            }
        }
        if (do_store) __builtin_nontemporal_store(res, op + s);
    };

    // ---- phase B issue: load slices [zlo+12, min(D,zlo+28)) into regs ----
    int zB0 = zlo + 12;
    int pcntB = (min(D_, zlo + 28) - zB0) * CPS_;
    f32x4 bv0, bv1, bv2, bv3, bv4;
    int   sl0, sl1, sl2, sl3, sl4;
    bool  bm0, bm1, bm2, bm3, bm4;
    {
#define ISSUE_B(J, BV, SL, BM)                                                 \
        {                                                                      \
            int c = tid + (J << 10);                                           \
            BM = c < pcntB;                                                    \
            int si  = c / CPS_;                                                \
            int rem = c - si * CPS_;                                           \
            int zs  = zB0 + si;                                                \
            SL = (zs - vz0) * SLICE_ + rem * 4;                                \
            if (BM) {                                                          \
                int row = rem / CPR_;                                          \
                int col = rem - row * CPR_;                                    \
                BV = *(const f32x4*)(im + (zs * H_ + ry + row) * W_ + rx + col * 4); \
            }                                                                  \
        }
        ISSUE_B(0, bv0, sl0, bm0)
        ISSUE_B(1, bv1, sl1, bm1)
        ISSUE_B(2, bv2, sl2, bm2)
        ISSUE_B(3, bv3, sl3, bm3)
        ISSUE_B(4, bv4, sl4, bm4)
#undef ISSUE_B
    }

    // ---- compute k=0,1 against phase-A window (slots 0..15 -> uz<=14) ----
    process(zlo + zz,     s0,           ddxv[0], ddy[0], ddz[0], 14);
    process(zlo + zz + 4, s0 + 4 * HW_, ddxv[1], ddy[1], ddz[1], 14);

    // ---- commit phase-B regs to LDS slots 16..31 (disjoint from A reads) --
    if (bm0) *(f32x4*)&tile[sl0] = bv0;
    if (bm1) *(f32x4*)&tile[sl1] = bv1;
    if (bm2) *(f32x4*)&tile[sl2] = bv2;
    if (bm3) *(f32x4*)&tile[sl3] = bv3;
    if (bm4) *(f32x4*)&tile[sl4] = bv4;
    __syncthreads();

    // ---- compute k=2..4 with the full window (uz<=30) ----
    process(zlo + zz + 8,  s0 + 8 * HW_,  ddxv[2], ddy[2], ddz[2], 30);
    process(zlo + zz + 12, s0 + 12 * HW_, ddxv[3], ddy[3], ddz[3], 30);
    process(zlo + zz + 16, s0 + 16 * HW_, ddxv[4], ddy[4], ddz[4], 30);

    __syncthreads();

    // ---- epilogue: resolve queued misses (ddf from queue, gathers L2-hot) --
    int n = min(qcount, QCAP_);
    for (int i = tid; i < n; i += 1024) {
        f32x4 q = qdat[i];
        int sq = __float_as_int(q.x);
        int zq = sq / HW_;
        int rq = sq - zq * HW_;
        int yq = rq / W_;
        int xq = rq - yq * W_;
        float res = gglobal(xq, yq, zq, q.y, q.z, q.w);
        op[sq] = res;
    }
}

extern "C" void kernel_launch(void* const* d_in, const int* in_sizes, int n_in,
                              void* d_out, int out_size, void* d_ws, size_t ws_size,
                              hipStream_t stream) {
    const float* img = (const float*)d_in[0];
    const float* ddf = (const float*)d_in[1];
    float*       out = (float*)d_out;

    warp3d_kernel<<<NBLK_, 1024, 0, stream>>>(img, ddf, out);
}